// Round 4
// baseline (258.451 us; speedup 1.0000x reference)
//
#include <hip/hip_runtime.h>
#include <stdint.h>

#define N_NODES 50000
#define F_IN 512
#define H_DIM 256
#define C_DIM 16
#define APITCH 520   // LDS row pitch in bf16 elems (1040 B)

typedef __attribute__((ext_vector_type(8))) short short8;
typedef __attribute__((ext_vector_type(4))) float f32x4;
typedef __attribute__((ext_vector_type(4))) unsigned short us4;
typedef __attribute__((ext_vector_type(8))) unsigned short us8;

__device__ inline float bf2f(unsigned short u) {
    return __uint_as_float(((uint32_t)u) << 16);
}
__device__ inline unsigned short f2bf(float f) {
    uint32_t u = __float_as_uint(f);
    u += 0x7FFFu + ((u >> 16) & 1u);   // round-to-nearest-even
    return (unsigned short)(u >> 16);
}
__device__ inline int eidx(const void* p, long long i, int is64) {
    return is64 ? (int)((const long long*)p)[i] : ((const int*)p)[i];
}

// ---------- fused prep: dtype detect + W1/W2 transpose-convert ----------

__global__ void prep_k(const void* ei, int* flag,
                       const float* w1, unsigned short* w1t,
                       const float* w2, unsigned short* w2t) {
    int i = blockIdx.x * 256 + threadIdx.x;
    if (i == 0) {
        const uint32_t* w = (const uint32_t*)ei;
        int is64 = 1;
        for (int j = 1; j < 128; j += 2)
            if (w[j] != 0u) { is64 = 0; break; }
        *flag = is64;
    }
    if (i < F_IN * H_DIM) {
        int k = i / H_DIM, n = i % H_DIM;
        w1t[n * F_IN + k] = f2bf(w1[i]);
    }
    if (i < H_DIM * C_DIM) {
        int k = i / C_DIM, n = i % C_DIM;
        w2t[n * H_DIM + k] = f2bf(w2[i]);
    }
}

// ---------- graph build ----------

__global__ void hist_k(const void* ei, const int* flag, int* cnt, long long E) {
    long long e = (long long)blockIdx.x * 256 + threadIdx.x;
    if (e >= E) return;
    int d = eidx(ei, E + e, *flag);
    atomicAdd(&cnt[d], 1);
}

__global__ __launch_bounds__(512) void scan1_k(const int* cnt, int* rowoff, int* bsum,
                                               float* dinv, int n) {
    __shared__ int s[512];
    int t = threadIdx.x;
    int i = blockIdx.x * 512 + t;
    int v = (i < n) ? cnt[i] : 0;
    s[t] = v;
    __syncthreads();
    for (int off = 1; off < 512; off <<= 1) {
        int add = (t >= off) ? s[t - off] : 0;
        __syncthreads();
        s[t] += add;
        __syncthreads();
    }
    if (i < n) {
        rowoff[i] = s[t] - v;                 // exclusive within chunk
        dinv[i] = rsqrtf((float)(v + 1));     // +1 self loop
    }
    if (t == 511) bsum[blockIdx.x] = s[511];
}

__global__ void scan2_k(int* bsum, int nb) {
    __shared__ int s[128];
    int t = threadIdx.x;
    int v = (t < nb) ? bsum[t] : 0;
    s[t] = v;
    __syncthreads();
    for (int off = 1; off < 128; off <<= 1) {
        int add = (t >= off) ? s[t - off] : 0;
        __syncthreads();
        s[t] += add;
        __syncthreads();
    }
    if (t < nb) bsum[t] = s[t] - v;     // exclusive block offsets
}

__global__ __launch_bounds__(512) void scan3_k(int* rowoff, const int* bsum, int n, int total) {
    int i = blockIdx.x * 512 + threadIdx.x;
    if (i < n) rowoff[i] += bsum[blockIdx.x];
    if (i == 0) rowoff[n] = total;
}

__global__ void scatter_k(const void* ei, const int* flag, const float* dinv,
                          const int* rowoff, int* cur, long long E, int2* colnorm) {
    long long e = (long long)blockIdx.x * 256 + threadIdx.x;
    if (e >= E) return;
    int is64 = *flag;
    int s = eidx(ei, e, is64);
    int d = eidx(ei, E + e, is64);
    int pos = rowoff[d] + atomicAdd(&cur[d], 1);
    float nrm = dinv[s] * dinv[d];
    int2 cn;
    cn.x = s;
    cn.y = __float_as_int(nrm);
    colnorm[pos] = cn;
}

// ---------- GEMM1: h1[50000x256] = bf16(x @ W1) via MFMA ----------
// Block: 64 rows x 256 cols, 8 waves (2M x 4N), acc[2][4], grid 782.
// A tile (64 rows) is CONTIGUOUS in x -> stage linearly: thread t loads
// float4 at flat idx pass*2048 + t*4 (wave-contiguous 1KB per instr, minimal
// line requests), converts to bf16, ds_write_b64 into pitched LDS.
// Compute: barrier-free, A from LDS, B from L2 with next-step reg prefetch.

__global__ __launch_bounds__(512, 4) void gemm1_k(const float* __restrict__ x,
                                                  const unsigned short* __restrict__ w1t,
                                                  unsigned short* __restrict__ h1) {
    __shared__ __align__(16) unsigned short As[64 * APITCH];   // 66,560 B

    const int t = threadIdx.x;
    const int wv = t >> 6, lane = t & 63;
    const int lg = lane >> 4, lr = lane & 15;
    const int wm = wv >> 2, wn = wv & 3;        // 2 x 4 wave grid

    // ---- linear coalesced stage ----
    {
        const long long TOT = (long long)N_NODES * F_IN;
        const long long base = (long long)blockIdx.x * (64 * F_IN) + t * 4;
        float4 v[8];
#pragma unroll
        for (int half = 0; half < 2; ++half) {
#pragma unroll
            for (int j = 0; j < 8; ++j) {
                long long idx = base + (half * 8 + j) * 2048;
                v[j] = (idx < TOT) ? *(const float4*)(x + idx)
                                   : make_float4(0.f, 0.f, 0.f, 0.f);
            }
#pragma unroll
            for (int j = 0; j < 8; ++j) {
                int loc = (half * 8 + j) * 2048 + t * 4;   // 0..32767
                int row = loc >> 9, col = loc & 511;
                us4 o;
                o.x = f2bf(v[j].x); o.y = f2bf(v[j].y);
                o.z = f2bf(v[j].z); o.w = f2bf(v[j].w);
                *(us4*)(As + row * APITCH + col) = o;
            }
        }
    }
    __syncthreads();

    // ---- barrier-free compute with B reg-prefetch ----
    const unsigned short* wp = w1t + (wn * 64 + lr) * F_IN + lg * 8;
    f32x4 acc[2][4] = {};
    short8 bc[4], bn[4];
#pragma unroll
    for (int ni = 0; ni < 4; ++ni)
        bc[ni] = *(const short8*)(wp + ni * 16 * F_IN);

#pragma unroll
    for (int ks = 0; ks < 16; ++ks) {
        if (ks < 15) {
#pragma unroll
            for (int ni = 0; ni < 4; ++ni)
                bn[ni] = *(const short8*)(wp + ni * 16 * F_IN + (ks + 1) * 32);
        }
        short8 a0 = *(const short8*)(As + (wm * 32 + lr) * APITCH + ks * 32 + lg * 8);
        short8 a1 = *(const short8*)(As + (wm * 32 + 16 + lr) * APITCH + ks * 32 + lg * 8);
#pragma unroll
        for (int ni = 0; ni < 4; ++ni)
            acc[0][ni] = __builtin_amdgcn_mfma_f32_16x16x32_bf16(a0, bc[ni], acc[0][ni], 0, 0, 0);
#pragma unroll
        for (int ni = 0; ni < 4; ++ni)
            acc[1][ni] = __builtin_amdgcn_mfma_f32_16x16x32_bf16(a1, bc[ni], acc[1][ni], 0, 0, 0);
        if (ks < 15) {
#pragma unroll
            for (int ni = 0; ni < 4; ++ni)
                bc[ni] = bn[ni];
        }
    }

    // epilogue: C layout col=lane&15, row=(lane>>4)*4+reg
#pragma unroll
    for (int mi = 0; mi < 2; ++mi)
#pragma unroll
        for (int ni = 0; ni < 4; ++ni)
#pragma unroll
            for (int j = 0; j < 4; ++j) {
                long long row = (long long)blockIdx.x * 64 + wm * 32 + mi * 16 + lg * 4 + j;
                if (row < N_NODES)
                    h1[row * H_DIM + wn * 64 + ni * 16 + lr] = f2bf(acc[mi][ni][j]);
            }
}

// ---------- Aggregation layer 1: h1a = bf16(relu(A_norm @ h1 + b1)) ----------
// 1 wave per dst node; half-wave (32 lanes x us8 = full 512B row) per edge;
// halves process even/odd edges, combined by shfl_xor(32).

__global__ __launch_bounds__(256) void agg1_k(const unsigned short* __restrict__ h1,
                                              const int* __restrict__ rowoff,
                                              const int2* __restrict__ colnorm,
                                              const float* __restrict__ dinv,
                                              const float* __restrict__ b1,
                                              unsigned short* __restrict__ h1a) {
    int wv = threadIdx.x >> 6, lane = threadIdx.x & 63;
    int node = blockIdx.x * 4 + wv;
    if (node >= N_NODES) return;
    int half = lane >> 5;
    int fl = (lane & 31) * 8;               // 8 features per lane
    int beg = rowoff[node], end = rowoff[node + 1];
    float a[8] = {0.f, 0.f, 0.f, 0.f, 0.f, 0.f, 0.f, 0.f};
    const unsigned short* base = h1 + fl;

    int e = beg + half;
    for (; e + 2 < end; e += 4) {           // 2 edges per half per iter
        int2 c0 = colnorm[e];
        int2 c1 = colnorm[e + 2];
        us8 v0 = *(const us8*)(base + (long long)c0.x * H_DIM);
        us8 v1 = *(const us8*)(base + (long long)c1.x * H_DIM);
        float n0 = __int_as_float(c0.y), n1 = __int_as_float(c1.y);
#pragma unroll
        for (int j = 0; j < 8; ++j)
            a[j] += n0 * bf2f(v0[j]) + n1 * bf2f(v1[j]);
    }
    if (e < end) {
        int2 c0 = colnorm[e];
        us8 v0 = *(const us8*)(base + (long long)c0.x * H_DIM);
        float n0 = __int_as_float(c0.y);
#pragma unroll
        for (int j = 0; j < 8; ++j)
            a[j] += n0 * bf2f(v0[j]);
    }
    // combine halves
#pragma unroll
    for (int j = 0; j < 8; ++j)
        a[j] += __shfl_xor(a[j], 32);

    if (half == 0) {
        float dn = dinv[node];
        float sn = dn * dn;
        us8 vs = *(const us8*)(base + (long long)node * H_DIM);
        float4 b0 = *(const float4*)(b1 + fl);
        float4 b4 = *(const float4*)(b1 + fl + 4);
        float bb[8] = {b0.x, b0.y, b0.z, b0.w, b4.x, b4.y, b4.z, b4.w};
        us8 o;
#pragma unroll
        for (int j = 0; j < 8; ++j) {
            float r = fmaxf(a[j] + sn * bf2f(vs[j]) + bb[j], 0.f);
            o[j] = f2bf(r);
        }
        *(us8*)(h1a + (long long)node * H_DIM + fl) = o;
    }
}

// ---------- GEMM2: h2[50000x16] = h1a @ W2 (MFMA straight from global) ----------

__global__ __launch_bounds__(256) void gemm2_k(const unsigned short* __restrict__ h1a,
                                               const unsigned short* __restrict__ w2t,
                                               float* __restrict__ h2) {
    int t = threadIdx.x;
    int wv = t >> 6, lane = t & 63, lg = lane >> 4, lr = lane & 15;
    int rbase = blockIdx.x * 64 + wv * 16;
    int rr = rbase + lr;
    int rc = rr < N_NODES ? rr : N_NODES - 1;
    f32x4 acc = {0.f, 0.f, 0.f, 0.f};
#pragma unroll
    for (int ks = 0; ks < 8; ++ks) {
        short8 a = *(const short8*)(h1a + (long long)rc * H_DIM + ks * 32 + lg * 8);
        short8 b = *(const short8*)(w2t + lr * H_DIM + ks * 32 + lg * 8);
        acc = __builtin_amdgcn_mfma_f32_16x16x32_bf16(a, b, acc, 0, 0, 0);
    }
#pragma unroll
    for (int j = 0; j < 4; ++j) {
        int row = rbase + lg * 4 + j;
        if (row < N_NODES) h2[(long long)row * C_DIM + lr] = acc[j];
    }
}

// ---------- Aggregation layer 2: out = A_norm @ h2 + b2 (fp32) ----------

__global__ __launch_bounds__(256) void agg2_k(const float* __restrict__ h2,
                                              const int* __restrict__ rowoff,
                                              const int2* __restrict__ colnorm,
                                              const float* __restrict__ dinv,
                                              const float* __restrict__ b2,
                                              float* __restrict__ out) {
    int g = threadIdx.x >> 4, c = threadIdx.x & 15;
    int node = blockIdx.x * 16 + g;
    if (node >= N_NODES) return;
    int beg = rowoff[node], end = rowoff[node + 1];
    float acc = 0.f;
    int e = beg;
    for (; e + 1 < end; e += 2) {
        int2 cn0 = colnorm[e];
        int2 cn1 = colnorm[e + 1];
        acc += __int_as_float(cn0.y) * h2[(long long)cn0.x * C_DIM + c]
             + __int_as_float(cn1.y) * h2[(long long)cn1.x * C_DIM + c];
    }
    if (e < end) {
        int2 cn = colnorm[e];
        acc += __int_as_float(cn.y) * h2[(long long)cn.x * C_DIM + c];
    }
    float dn = dinv[node];
    acc += dn * dn * h2[(long long)node * C_DIM + c];
    out[(long long)node * C_DIM + c] = acc + b2[c];
}

// ---------- launch ----------

extern "C" void kernel_launch(void* const* d_in, const int* in_sizes, int n_in,
                              void* d_out, int out_size, void* d_ws, size_t ws_size,
                              hipStream_t stream) {
    const float* x  = (const float*)d_in[0];
    const void*  ei = d_in[1];
    const float* W1 = (const float*)d_in[2];
    const float* b1 = (const float*)d_in[3];
    const float* W2 = (const float*)d_in[4];
    const float* b2 = (const float*)d_in[5];
    float* out = (float*)d_out;
    long long E = (long long)in_sizes[1] / 2;

    char* w = (char*)d_ws;
    auto alloc = [&](size_t bytes) -> char* {
        char* p = w;
        w += (bytes + 255) & ~(size_t)255;
        return p;
    };
    int*   flag    = (int*)   alloc(4);
    int*   cnt     = (int*)   alloc((size_t)N_NODES * 4);
    int*   cur     = (int*)   alloc((size_t)N_NODES * 4);
    float* dinv    = (float*) alloc((size_t)N_NODES * 4);
    int*   rowoff  = (int*)   alloc((size_t)(N_NODES + 1) * 4);
    int*   bsum    = (int*)   alloc(512 * 4);
    int2*  colnorm = (int2*)  alloc((size_t)E * 8);
    unsigned short* w1t = (unsigned short*)alloc((size_t)H_DIM * F_IN * 2);
    unsigned short* w2t = (unsigned short*)alloc((size_t)C_DIM * H_DIM * 2);
    unsigned short* h1  = (unsigned short*)alloc((size_t)N_NODES * H_DIM * 2);
    unsigned short* h1a = (unsigned short*)alloc((size_t)N_NODES * H_DIM * 2);
    float* h2 = (float*)alloc((size_t)N_NODES * C_DIM * 4);

    hipMemsetAsync(cnt, 0, (size_t)N_NODES * 4, stream);
    hipMemsetAsync(cur, 0, (size_t)N_NODES * 4, stream);
    prep_k<<<(F_IN * H_DIM + 255) / 256, 256, 0, stream>>>(ei, flag, W1, w1t, W2, w2t);

    int egrid = (int)((E + 255) / 256);
    hist_k<<<egrid, 256, 0, stream>>>(ei, flag, cnt, E);
    int sgrid = (N_NODES + 511) / 512;   // 98 (<=128 for scan2)
    scan1_k<<<sgrid, 512, 0, stream>>>(cnt, rowoff, bsum, dinv, N_NODES);
    scan2_k<<<1, 128, 0, stream>>>(bsum, sgrid);
    scan3_k<<<sgrid, 512, 0, stream>>>(rowoff, bsum, N_NODES, (int)E);
    scatter_k<<<egrid, 256, 0, stream>>>(ei, flag, dinv, rowoff, cur, E, colnorm);

    gemm1_k<<<(N_NODES + 63) / 64, 512, 0, stream>>>(x, w1t, h1);
    agg1_k<<<(N_NODES + 3) / 4, 256, 0, stream>>>(h1, rowoff, colnorm, dinv, b1, h1a);
    gemm2_k<<<(N_NODES + 63) / 64, 256, 0, stream>>>(h1a, w2t, h2);
    agg2_k<<<(N_NODES + 15) / 16, 256, 0, stream>>>(h2, rowoff, colnorm, dinv, b2, out);
}

// Round 5
// 217.473 us; speedup vs baseline: 1.1884x; 1.1884x over previous
//
#include <hip/hip_runtime.h>
#include <stdint.h>

#define N_NODES 50000
#define F_IN 512
#define H_DIM 256
#define C_DIM 16

typedef __attribute__((ext_vector_type(8))) short short8;
typedef __attribute__((ext_vector_type(4))) float f32x4;
typedef __attribute__((ext_vector_type(4))) unsigned short us4;
typedef __attribute__((ext_vector_type(8))) unsigned short us8;

__device__ inline float bf2f(unsigned short u) {
    return __uint_as_float(((uint32_t)u) << 16);
}
__device__ inline unsigned short f2bf(float f) {
    uint32_t u = __float_as_uint(f);
    u += 0x7FFFu + ((u >> 16) & 1u);   // round-to-nearest-even
    return (unsigned short)(u >> 16);
}
__device__ inline int eidx(const void* p, long long i, int is64) {
    return is64 ? (int)((const long long*)p)[i] : ((const int*)p)[i];
}

// ---------- fused prep: dtype detect + W1/W2 transpose-convert ----------

__global__ void prep_k(const void* ei, int* flag,
                       const float* w1, unsigned short* w1t,
                       const float* w2, unsigned short* w2t) {
    int i = blockIdx.x * 256 + threadIdx.x;
    if (i == 0) {
        const uint32_t* w = (const uint32_t*)ei;
        int is64 = 1;
        for (int j = 1; j < 128; j += 2)
            if (w[j] != 0u) { is64 = 0; break; }
        *flag = is64;
    }
    if (i < F_IN * H_DIM) {
        int k = i / H_DIM, n = i % H_DIM;
        w1t[n * F_IN + k] = f2bf(w1[i]);
    }
    if (i < H_DIM * C_DIM) {
        int k = i / C_DIM, n = i % C_DIM;
        w2t[n * H_DIM + k] = f2bf(w2[i]);
    }
}

// ---------- graph build ----------

__global__ void hist_k(const void* ei, const int* flag, int* cnt, long long E) {
    long long e = (long long)blockIdx.x * 256 + threadIdx.x;
    if (e >= E) return;
    int d = eidx(ei, E + e, *flag);
    atomicAdd(&cnt[d], 1);
}

__global__ __launch_bounds__(512) void scan1_k(const int* cnt, int* rowoff, int* bsum,
                                               float* dinv, int n) {
    __shared__ int s[512];
    int t = threadIdx.x;
    int i = blockIdx.x * 512 + t;
    int v = (i < n) ? cnt[i] : 0;
    s[t] = v;
    __syncthreads();
    for (int off = 1; off < 512; off <<= 1) {
        int add = (t >= off) ? s[t - off] : 0;
        __syncthreads();
        s[t] += add;
        __syncthreads();
    }
    if (i < n) {
        rowoff[i] = s[t] - v;                 // exclusive within chunk
        dinv[i] = rsqrtf((float)(v + 1));     // +1 self loop
    }
    if (t == 511) bsum[blockIdx.x] = s[511];
}

__global__ void scan2_k(int* bsum, int nb) {
    __shared__ int s[128];
    int t = threadIdx.x;
    int v = (t < nb) ? bsum[t] : 0;
    s[t] = v;
    __syncthreads();
    for (int off = 1; off < 128; off <<= 1) {
        int add = (t >= off) ? s[t - off] : 0;
        __syncthreads();
        s[t] += add;
        __syncthreads();
    }
    if (t < nb) bsum[t] = s[t] - v;     // exclusive block offsets
}

__global__ __launch_bounds__(512) void scan3_k(int* rowoff, const int* bsum, int n, int total) {
    int i = blockIdx.x * 512 + threadIdx.x;
    if (i < n) rowoff[i] += bsum[blockIdx.x];
    if (i == 0) rowoff[n] = total;
}

__global__ void scatter_k(const void* ei, const int* flag, const float* dinv,
                          const int* rowoff, int* cur, long long E, int2* colnorm) {
    long long e = (long long)blockIdx.x * 256 + threadIdx.x;
    if (e >= E) return;
    int is64 = *flag;
    int s = eidx(ei, e, is64);
    int d = eidx(ei, E + e, is64);
    int pos = rowoff[d] + atomicAdd(&cur[d], 1);
    float nrm = dinv[s] * dinv[d];
    int2 cn;
    cn.x = s;
    cn.y = __float_as_int(nrm);
    colnorm[pos] = cn;
}

// ---------- GEMM1: h1[50000x256] = bf16(x @ W1) via MFMA ----------
// Tile 64M x 256N, BK=64, 4 waves (wave = full 64M x 64N), grid 782.
// BOTH operands in double-buffered LDS (B cooperatively staged -> no per-wave
// L2-latency chain in the MFMA loop, the r1-r4 limiter). 128-B LDS rows with
// chunk-XOR swizzle (c ^= row&7): conflict-free ds_write AND ds_read_b128.
// Reg-staged (A needs fp32->bf16), loads for step k+2 issued after step
// k+1's regs are consumed -> ds_write waits ~1 compute phase after issue.
// One __syncthreads per K-step.

__global__ __launch_bounds__(256, 2) void gemm1_k(const float* __restrict__ x,
                                                  const unsigned short* __restrict__ w1t,
                                                  unsigned short* __restrict__ h1) {
    __shared__ __align__(16) unsigned short As[2][64 * 64];     // 16 KB
    __shared__ __align__(16) unsigned short Bs[2][256 * 64];    // 64 KB

    const int t = threadIdx.x;
    const int wn = t >> 6, lane = t & 63;
    const int lg = lane >> 4, lr = lane & 15;

    f32x4 acc[4][4] = {};

    // A staging geometry: thread covers row ra, float quarter kq (16 floats)
    const int ra = t >> 2;
    const int kq = t & 3;
    const long long grow = (long long)blockIdx.x * 64 + ra;
    const bool aok = grow < N_NODES;
    const float* xp = aok ? (x + grow * F_IN + kq * 16) : x;
    const int c0a = kq * 2, rsa = ra & 7;
    // B staging geometry: iteration j covers row (t>>3)+j*32, chunk t&7
    const unsigned short* bp = w1t + (t >> 3) * F_IN + (t & 7) * 8;
    const int csb = (t & 7) ^ ((t >> 3) & 7);

    float4 av[4];
    us8 bv[8];

#define SLOAD(ks)                                                             \
    do { const int _k0 = (ks) * 64;                                           \
        if (aok) { _Pragma("unroll") for (int j = 0; j < 4; ++j)              \
            av[j] = *(const float4*)(xp + _k0 + j * 4);                       \
        } else { _Pragma("unroll") for (int j = 0; j < 4; ++j)                \
            av[j] = make_float4(0.f, 0.f, 0.f, 0.f); }                        \
        _Pragma("unroll") for (int j = 0; j < 8; ++j)                         \
            bv[j] = *(const us8*)(bp + j * 32 * F_IN + _k0);                  \
    } while (0)

#define SWRITE(bf)                                                            \
    do { us8 _w0, _w1;                                                        \
        _w0[0] = f2bf(av[0].x); _w0[1] = f2bf(av[0].y);                       \
        _w0[2] = f2bf(av[0].z); _w0[3] = f2bf(av[0].w);                       \
        _w0[4] = f2bf(av[1].x); _w0[5] = f2bf(av[1].y);                       \
        _w0[6] = f2bf(av[1].z); _w0[7] = f2bf(av[1].w);                       \
        _w1[0] = f2bf(av[2].x); _w1[1] = f2bf(av[2].y);                       \
        _w1[2] = f2bf(av[2].z); _w1[3] = f2bf(av[2].w);                       \
        _w1[4] = f2bf(av[3].x); _w1[5] = f2bf(av[3].y);                       \
        _w1[6] = f2bf(av[3].z); _w1[7] = f2bf(av[3].w);                       \
        *(us8*)&As[bf][ra * 64 + ((c0a ^ rsa) * 8)] = _w0;                    \
        *(us8*)&As[bf][ra * 64 + (((c0a + 1) ^ rsa) * 8)] = _w1;              \
        _Pragma("unroll") for (int j = 0; j < 8; ++j)                         \
            *(us8*)&Bs[bf][((t >> 3) + j * 32) * 64 + csb * 8] = bv[j];       \
    } while (0)

#define COMPUTE(bf)                                                           \
    do { _Pragma("unroll") for (int ksub = 0; ksub < 2; ++ksub) {             \
        short8 afr[4], bfr[4];                                                \
        _Pragma("unroll") for (int mi = 0; mi < 4; ++mi) {                    \
            int _r = mi * 16 + lr;                                            \
            afr[mi] = *(const short8*)                                        \
                &As[bf][_r * 64 + (((ksub * 4 + lg) ^ (_r & 7)) * 8)]; }      \
        _Pragma("unroll") for (int ni = 0; ni < 4; ++ni) {                    \
            int _r = wn * 64 + ni * 16 + lr;                                  \
            bfr[ni] = *(const short8*)                                        \
                &Bs[bf][_r * 64 + (((ksub * 4 + lg) ^ (_r & 7)) * 8)]; }      \
        _Pragma("unroll") for (int mi = 0; mi < 4; ++mi)                      \
            _Pragma("unroll") for (int ni = 0; ni < 4; ++ni)                  \
                acc[mi][ni] = __builtin_amdgcn_mfma_f32_16x16x32_bf16(        \
                    afr[mi], bfr[ni], acc[mi][ni], 0, 0, 0);                  \
    } } while (0)

    // prologue
    SLOAD(0);
    SWRITE(0);
    SLOAD(1);
    __syncthreads();

    for (int ks = 0; ks < 8; ++ks) {
        const int cur = ks & 1;
        if (ks + 1 < 8) SWRITE(1 - cur);   // stage regs(ks+1) -> other buffer
        if (ks + 2 < 8) SLOAD(ks + 2);     // issue next loads (in flight)
        COMPUTE(cur);
        __syncthreads();
    }
#undef SLOAD
#undef SWRITE
#undef COMPUTE

    // epilogue: C layout col=lane&15 (N), row=(lane>>4)*4+reg (M)
#pragma unroll
    for (int mi = 0; mi < 4; ++mi)
#pragma unroll
        for (int ni = 0; ni < 4; ++ni)
#pragma unroll
            for (int j = 0; j < 4; ++j) {
                long long row = (long long)blockIdx.x * 64 + mi * 16 + lg * 4 + j;
                if (row < N_NODES)
                    h1[row * H_DIM + wn * 64 + ni * 16 + lr] = f2bf(acc[mi][ni][j]);
            }
}

// ---------- Aggregation layer 1: h1a = bf16(relu(A_norm @ h1 + b1)) ----------
// 1 wave per dst node; half-wave (32 lanes x us8 = full 512B row) per edge;
// halves process even/odd edges (4-deep ILP), combined by shfl_xor(32).

__global__ __launch_bounds__(256) void agg1_k(const unsigned short* __restrict__ h1,
                                              const int* __restrict__ rowoff,
                                              const int2* __restrict__ colnorm,
                                              const float* __restrict__ dinv,
                                              const float* __restrict__ b1,
                                              unsigned short* __restrict__ h1a) {
    int wv = threadIdx.x >> 6, lane = threadIdx.x & 63;
    int node = blockIdx.x * 4 + wv;
    if (node >= N_NODES) return;
    int half = lane >> 5;
    int fl = (lane & 31) * 8;               // 8 features per lane
    int beg = rowoff[node], end = rowoff[node + 1];
    float a[8] = {0.f, 0.f, 0.f, 0.f, 0.f, 0.f, 0.f, 0.f};
    const unsigned short* base = h1 + fl;

    int e = beg + half;
    while (e + 6 < end) {                   // 4 edges per half in flight
        int2 c[4];
        us8 v[4];
#pragma unroll
        for (int q = 0; q < 4; ++q) c[q] = colnorm[e + q * 2];
#pragma unroll
        for (int q = 0; q < 4; ++q)
            v[q] = *(const us8*)(base + (long long)c[q].x * H_DIM);
#pragma unroll
        for (int q = 0; q < 4; ++q) {
            float n = __int_as_float(c[q].y);
#pragma unroll
            for (int j = 0; j < 8; ++j) a[j] += n * bf2f(v[q][j]);
        }
        e += 8;
    }
    while (e < end) {
        int2 c0 = colnorm[e];
        us8 v0 = *(const us8*)(base + (long long)c0.x * H_DIM);
        float n0 = __int_as_float(c0.y);
#pragma unroll
        for (int j = 0; j < 8; ++j) a[j] += n0 * bf2f(v0[j]);
        e += 2;
    }
    // combine halves
#pragma unroll
    for (int j = 0; j < 8; ++j)
        a[j] += __shfl_xor(a[j], 32);

    if (half == 0) {
        float dn = dinv[node];
        float sn = dn * dn;
        us8 vs = *(const us8*)(base + (long long)node * H_DIM);
        float4 b0 = *(const float4*)(b1 + fl);
        float4 b4 = *(const float4*)(b1 + fl + 4);
        float bb[8] = {b0.x, b0.y, b0.z, b0.w, b4.x, b4.y, b4.z, b4.w};
        us8 o;
#pragma unroll
        for (int j = 0; j < 8; ++j) {
            float r = fmaxf(a[j] + sn * bf2f(vs[j]) + bb[j], 0.f);
            o[j] = f2bf(r);
        }
        *(us8*)(h1a + (long long)node * H_DIM + fl) = o;
    }
}

// ---------- GEMM2: h2[50000x16] = h1a @ W2 (MFMA straight from global) ----------

__global__ __launch_bounds__(256) void gemm2_k(const unsigned short* __restrict__ h1a,
                                               const unsigned short* __restrict__ w2t,
                                               float* __restrict__ h2) {
    int t = threadIdx.x;
    int wv = t >> 6, lane = t & 63, lg = lane >> 4, lr = lane & 15;
    int rbase = blockIdx.x * 64 + wv * 16;
    int rr = rbase + lr;
    int rc = rr < N_NODES ? rr : N_NODES - 1;
    f32x4 acc = {0.f, 0.f, 0.f, 0.f};
#pragma unroll
    for (int ks = 0; ks < 8; ++ks) {
        short8 a = *(const short8*)(h1a + (long long)rc * H_DIM + ks * 32 + lg * 8);
        short8 b = *(const short8*)(w2t + lr * H_DIM + ks * 32 + lg * 8);
        acc = __builtin_amdgcn_mfma_f32_16x16x32_bf16(a, b, acc, 0, 0, 0);
    }
#pragma unroll
    for (int j = 0; j < 4; ++j) {
        int row = rbase + lg * 4 + j;
        if (row < N_NODES) h2[(long long)row * C_DIM + lr] = acc[j];
    }
}

// ---------- Aggregation layer 2: out = A_norm @ h2 + b2 (fp32) ----------

__global__ __launch_bounds__(256) void agg2_k(const float* __restrict__ h2,
                                              const int* __restrict__ rowoff,
                                              const int2* __restrict__ colnorm,
                                              const float* __restrict__ dinv,
                                              const float* __restrict__ b2,
                                              float* __restrict__ out) {
    int g = threadIdx.x >> 4, c = threadIdx.x & 15;
    int node = blockIdx.x * 16 + g;
    if (node >= N_NODES) return;
    int beg = rowoff[node], end = rowoff[node + 1];
    float acc = 0.f;
    int e = beg;
    for (; e + 1 < end; e += 2) {
        int2 cn0 = colnorm[e];
        int2 cn1 = colnorm[e + 1];
        acc += __int_as_float(cn0.y) * h2[(long long)cn0.x * C_DIM + c]
             + __int_as_float(cn1.y) * h2[(long long)cn1.x * C_DIM + c];
    }
    if (e < end) {
        int2 cn = colnorm[e];
        acc += __int_as_float(cn.y) * h2[(long long)cn.x * C_DIM + c];
    }
    float dn = dinv[node];
    acc += dn * dn * h2[(long long)node * C_DIM + c];
    out[(long long)node * C_DIM + c] = acc + b2[c];
}

// ---------- launch ----------

extern "C" void kernel_launch(void* const* d_in, const int* in_sizes, int n_in,
                              void* d_out, int out_size, void* d_ws, size_t ws_size,
                              hipStream_t stream) {
    const float* x  = (const float*)d_in[0];
    const void*  ei = d_in[1];
    const float* W1 = (const float*)d_in[2];
    const float* b1 = (const float*)d_in[3];
    const float* W2 = (const float*)d_in[4];
    const float* b2 = (const float*)d_in[5];
    float* out = (float*)d_out;
    long long E = (long long)in_sizes[1] / 2;

    char* w = (char*)d_ws;
    auto alloc = [&](size_t bytes) -> char* {
        char* p = w;
        w += (bytes + 255) & ~(size_t)255;
        return p;
    };
    int*   flag    = (int*)   alloc(4);
    int*   cnt     = (int*)   alloc((size_t)N_NODES * 4);
    int*   cur     = (int*)   alloc((size_t)N_NODES * 4);
    float* dinv    = (float*) alloc((size_t)N_NODES * 4);
    int*   rowoff  = (int*)   alloc((size_t)(N_NODES + 1) * 4);
    int*   bsum    = (int*)   alloc(512 * 4);
    int2*  colnorm = (int2*)  alloc((size_t)E * 8);
    unsigned short* w1t = (unsigned short*)alloc((size_t)H_DIM * F_IN * 2);
    unsigned short* w2t = (unsigned short*)alloc((size_t)C_DIM * H_DIM * 2);
    unsigned short* h1  = (unsigned short*)alloc((size_t)N_NODES * H_DIM * 2);
    unsigned short* h1a = (unsigned short*)alloc((size_t)N_NODES * H_DIM * 2);
    float* h2 = (float*)alloc((size_t)N_NODES * C_DIM * 4);

    hipMemsetAsync(cnt, 0, (size_t)N_NODES * 4, stream);
    hipMemsetAsync(cur, 0, (size_t)N_NODES * 4, stream);
    prep_k<<<(F_IN * H_DIM + 255) / 256, 256, 0, stream>>>(ei, flag, W1, w1t, W2, w2t);

    int egrid = (int)((E + 255) / 256);
    hist_k<<<egrid, 256, 0, stream>>>(ei, flag, cnt, E);
    int sgrid = (N_NODES + 511) / 512;   // 98 (<=128 for scan2)
    scan1_k<<<sgrid, 512, 0, stream>>>(cnt, rowoff, bsum, dinv, N_NODES);
    scan2_k<<<1, 128, 0, stream>>>(bsum, sgrid);
    scan3_k<<<sgrid, 512, 0, stream>>>(rowoff, bsum, N_NODES, (int)E);
    scatter_k<<<egrid, 256, 0, stream>>>(ei, flag, dinv, rowoff, cur, E, colnorm);

    gemm1_k<<<(N_NODES + 63) / 64, 256, 0, stream>>>(x, w1t, h1);
    agg1_k<<<(N_NODES + 3) / 4, 256, 0, stream>>>(h1, rowoff, colnorm, dinv, b1, h1a);
    gemm2_k<<<(N_NODES + 63) / 64, 256, 0, stream>>>(h1a, w2t, h2);
    agg2_k<<<(N_NODES + 15) / 16, 256, 0, stream>>>(h2, rowoff, colnorm, dinv, b2, out);
}